// Round 7
// baseline (289.168 us; speedup 1.0000x reference)
//
#include <hip/hip_runtime.h>

// MoE: M=4096, K=1024, E=8, N=1024, TOPK=2
// out[m] = sum_t topk_w[m,t] * ( silu(hs[m]@w1[e][:, :N]) * (hs[m]@w1[e][:, N:]) ) @ w2[e]

#define M_TOK   4096
#define K_DIM   1024
#define N_DIM   1024
#define E_NUM   8
#define NPAIR   8192            // M_TOK * TOPK
#define BM      128
#define ROWS_CAP 9216           // NPAIR + E_NUM*BM
#define NROWBLK 72              // ROWS_CAP / BM
#define HBLK    32              // routing hist blocks (NPAIR / 256)
#define NK      16              // K_DIM / 64

typedef unsigned short u16;
typedef unsigned int   u32;
typedef __attribute__((ext_vector_type(8))) short bf16x8;
typedef __attribute__((ext_vector_type(4))) float f32x4;

#define GPTR(p) ((const __attribute__((address_space(1))) u32*)(const void*)(p))
#define LPTR(p) ((__attribute__((address_space(3))) u32*)(void*)(p))

__device__ __forceinline__ u16 f2bf(float f) {
  union { float f; u32 u; } v; v.f = f;
  u32 r = v.u + 0x7FFFu + ((v.u >> 16) & 1u);   // RNE
  return (u16)(r >> 16);
}
__device__ __forceinline__ float bf2f(u16 u) {
  union { u32 u; float f; } v; v.u = ((u32)u) << 16;
  return v.f;
}

// ---------------- prep: convert hs + transpose w1/w2 + routing hist -----------
__device__ __forceinline__ void transpose_body(
    const float* __restrict__ in, u16* __restrict__ out, int R, int Cc,
    int xt, int yt, int zt, float (*lds)[65]) {
  const float* src = in + (size_t)zt * R * Cc;
  u16* dst = out + (size_t)zt * R * Cc;
  int r0 = xt * 64, c0 = yt * 64;
  int t = threadIdx.x;
#pragma unroll
  for (int it = 0; it < 16; ++it) {
    int lin = it * 256 + t;
    int rr = lin >> 6, cc = lin & 63;
    lds[cc][rr] = src[(size_t)(r0 + rr) * Cc + c0 + cc];
  }
  __syncthreads();
#pragma unroll
  for (int it = 0; it < 8; ++it) {
    int lin = it * 512 + t * 2;
    int cc = lin >> 6, rr = lin & 63;
    ushort2 o;
    o.x = f2bf(lds[cc][rr]);
    o.y = f2bf(lds[cc][rr + 1]);
    *(ushort2*)&dst[(size_t)(c0 + cc) * R + r0 + rr] = o;
  }
}

__global__ __launch_bounds__(256) void prep_kernel(
    const float* __restrict__ hs, const float* __restrict__ w1,
    const float* __restrict__ w2, const int* __restrict__ topk_ids,
    u16* __restrict__ hsb, u16* __restrict__ w1t, u16* __restrict__ w2t,
    int* __restrict__ blockhist) {
  __shared__ float tlds[64][65];
  __shared__ int wcnt[4][E_NUM];
  const int b = blockIdx.x, t = threadIdx.x;
  if (b < 4096) {                       // hs fp32 -> bf16
    int i = b * 256 + t;
    float4 v = ((const float4*)hs)[i];
    ushort4 o;
    o.x = f2bf(v.x); o.y = f2bf(v.y); o.z = f2bf(v.z); o.w = f2bf(v.w);
    ((ushort4*)hsb)[i] = o;
  } else if (b < 8192) {                // w1 (E,K,2N) -> (E,2N,K)
    int idx = b - 4096;
    transpose_body(w1, w1t, 1024, 2048, idx & 15, (idx >> 4) & 31, idx >> 9, tlds);
  } else if (b < 10240) {               // w2 (E,N,K) -> (E,K,N)
    int idx = b - 8192;
    transpose_body(w2, w2t, 1024, 1024, idx & 15, (idx >> 4) & 15, idx >> 8, tlds);
  } else {                              // routing histogram
    int blk = b - 10240;
    const int wave = t >> 6, lane = t & 63;
    int e = topk_ids[blk * 256 + t] & 7;
#pragma unroll
    for (int ee = 0; ee < E_NUM; ++ee) {
      unsigned long long m = __ballot(e == ee);
      if (lane == ee) wcnt[wave][ee] = (int)__popcll(m);
    }
    __syncthreads();
    if (t < E_NUM)
      blockhist[blk * E_NUM + t] = wcnt[0][t] + wcnt[1][t] + wcnt[2][t] + wcnt[3][t];
  }
}

// ---------------- routing stage 2: scan, offsets, block_expert, pad fill ------
__global__ __launch_bounds__(256) void scan_kernel(
    const int* __restrict__ blockhist, int* __restrict__ baseoff,
    int* __restrict__ pair_token, int* __restrict__ block_expert) {
  __shared__ int cnt[E_NUM], off[E_NUM], pad[E_NUM];
  const int t = threadIdx.x;
  if (t < E_NUM) {
    int run = 0;
    for (int b = 0; b < HBLK; ++b) {
      baseoff[b * E_NUM + t] = run;
      run += blockhist[b * E_NUM + t];
    }
    cnt[t] = run;
  }
  __syncthreads();
  if (t == 0) {
    int run = 0, blk = 0;
    for (int e = 0; e < E_NUM; ++e) {
      off[e] = run;
      int padded = ((cnt[e] + BM - 1) / BM) * BM;
      pad[e] = padded;
      for (int b = 0; b < padded / BM; ++b) block_expert[blk++] = e;
      run += padded;
    }
    for (; blk < NROWBLK; ++blk) block_expert[blk] = -1;
  }
  __syncthreads();
  for (int i = t; i < HBLK * E_NUM; i += 256) baseoff[i] += off[i & 7];
  for (int e = 0; e < E_NUM; ++e) {
    int s = off[e] + cnt[e], epos = off[e] + pad[e];
    for (int r = s + t; r < epos; r += 256) pair_token[r] = 0;
  }
}

// ---------------- routing stage 3: deterministic position assignment ----------
__global__ __launch_bounds__(256) void assign_kernel(
    const int* __restrict__ topk_ids, const int* __restrict__ baseoff,
    int* __restrict__ pair_token, int* __restrict__ pos_of) {
  __shared__ int wcnt[4][E_NUM], wbase[4][E_NUM];
  const int t = threadIdx.x, wave = t >> 6, lane = t & 63;
  const int p = blockIdx.x * 256 + t;
  const int e = topk_ids[p] & 7;
  int rank = 0;
#pragma unroll
  for (int ee = 0; ee < E_NUM; ++ee) {
    unsigned long long m = __ballot(e == ee);
    if (e == ee) rank = (int)__popcll(m & ((1ull << lane) - 1ull));
    if (lane == ee) wcnt[wave][ee] = (int)__popcll(m);
  }
  __syncthreads();
  if (t < E_NUM) {
    int run = baseoff[blockIdx.x * E_NUM + t];
    for (int w = 0; w < 4; ++w) { wbase[w][t] = run; run += wcnt[w][t]; }
  }
  __syncthreads();
  int pos = wbase[wave][e] + rank;
  pair_token[pos] = p >> 1;
  pos_of[p] = pos;
}

// ---------------- big-tile dbuf grouped GEMM: 128 rows x 256 cols -------------
// 512 threads / 8 waves (2 per SIMD). Per 64-k iter: stage 48 KB (A 16 + B 32)
// for 4.2 MFLOP = 87 FLOP/B. Wave w: rows (w>>2)*64, cols (w&3)*32 in BOTH
// 128-col groups (nb) -> silu pairs in-register for GEMM1. Single barrier per
// iter: barrier -> prefetch into buf[1-cur] -> compute buf[cur]; prefetch has
// ~1088 cyc (full compute phase) in flight before the next barrier drains it.
template <bool GATHER, bool SILU, int NBY>
__global__ __launch_bounds__(512, 2) void gemm_big(
    const u16* __restrict__ A, const u16* __restrict__ Bt, u16* __restrict__ Out,
    const int* __restrict__ pair_token, const int* __restrict__ block_expert) {
  const int by = blockIdx.x % NBY;      // col-block: consecutive ids -> XCDs
  const int rbk = blockIdx.x / NBY;     // row-block: stride-NBY share XCD+B
  const int e = block_expert[rbk];
  if (e < 0) return;
  __shared__ __align__(16) u16 As[2 * 8192];    // 2 x (128 rows x 64 k)
  __shared__ __align__(16) u16 Bs[2 * 16384];   // 2 x (256 cols x 64 k)
  const int tid = threadIdx.x;
  const int w = tid >> 6;
  const int lane = tid & 63;
  const int lr = lane >> 3;             // staging row within 8-row shot
  const int lc = lane & 7;              // chunk position

  const int cb0 = SILU ? by * 128 : by * 256;          // gate / first col group
  const int cb1 = SILU ? N_DIM + by * 128 : by * 256 + 128;  // up / second

  const u16* ap[2];
#pragma unroll
  for (int inst = 0; inst < 2; ++inst) {
    int row = w * 16 + inst * 8 + lr;
    int grow = rbk * BM + row;
    int arow = GATHER ? pair_token[grow] : grow;
    ap[inst] = A + (size_t)arow * K_DIM + (((lc ^ (row & 7)) << 3));
  }
  const u16* bp[4];
  const u16* base_e = Bt + (size_t)e * (2 * N_DIM) * K_DIM;
  const u16* base_e2 = SILU ? base_e : Bt + (size_t)e * N_DIM * K_DIM;  // w2t: (E,K,N) rows=K_DIM
#pragma unroll
  for (int inst = 0; inst < 4; ++inst) {
    int br = w * 32 + inst * 8 + lr;    // Bs row 0..255
    int rg = (br < 128) ? (cb0 + br) : (cb1 + (br - 128));
    bp[inst] = base_e2 + (size_t)rg * K_DIM + ((lc ^ (br & 7)) << 3);
  }

  f32x4 acc[2][4][2];                   // [nb][i(row16)][j(col16)]
#pragma unroll
  for (int nb = 0; nb < 2; ++nb)
#pragma unroll
    for (int i = 0; i < 4; ++i)
#pragma unroll
      for (int j = 0; j < 2; ++j) acc[nb][i][j] = f32x4{0.f, 0.f, 0.f, 0.f};

  const int wm = (w >> 2) * 64;         // wave row base
  const int wn = (w & 3) * 32;          // wave col base (within 128-col group)

#define STAGE(it, buf)                                                         \
  {                                                                            \
    _Pragma("unroll") for (int inst = 0; inst < 2; ++inst)                     \
      __builtin_amdgcn_global_load_lds(GPTR(ap[inst] + (it) * 64),             \
          LPTR(As + (buf) * 8192 + (w * 16 + inst * 8) * 64), 16, 0, 0);       \
    _Pragma("unroll") for (int inst = 0; inst < 4; ++inst)                     \
      __builtin_amdgcn_global_load_lds(GPTR(bp[inst] + (it) * 64),             \
          LPTR(Bs + (buf) * 16384 + (w * 32 + inst * 8) * 64), 16, 0, 0);      \
  }

#define HALF(it, cur)                                                          \
  {                                                                            \
    __syncthreads();                  /* buf[cur] landed, buf[1-cur] free */   \
    if ((it) + 1 < NK) STAGE((it) + 1, 1 - (cur));                             \
    _Pragma("unroll") for (int ks = 0; ks < 2; ++ks) {                         \
      const int cq = ks * 4 + (lane >> 4);                                     \
      bf16x8 af[4], bfr[2][2];                                                 \
      _Pragma("unroll") for (int i = 0; i < 4; ++i) {                          \
        int row = wm + i * 16 + (lane & 15);                                   \
        af[i] = *(const bf16x8*)&As[(cur) * 8192 + row * 64 +                  \
                                    ((cq ^ (row & 7)) << 3)];                  \
      }                                                                        \
      _Pragma("unroll") for (int nb = 0; nb < 2; ++nb)                         \
        _Pragma("unroll") for (int j = 0; j < 2; ++j) {                        \
          int br = nb * 128 + wn + j * 16 + (lane & 15);                       \
          bfr[nb][j] = *(const bf16x8*)&Bs[(cur) * 16384 + br * 64 +           \
                                           ((cq ^ (br & 7)) << 3)];            \
        }                                                                      \
      _Pragma("unroll") for (int nb = 0; nb < 2; ++nb)                         \
        _Pragma("unroll") for (int i = 0; i < 4; ++i)                          \
          _Pragma("unroll") for (int j = 0; j < 2; ++j)                        \
            acc[nb][i][j] = __builtin_amdgcn_mfma_f32_16x16x32_bf16(           \
                af[i], bfr[nb][j], acc[nb][i][j], 0, 0, 0);                    \
    }                                                                          \
  }

  STAGE(0, 0);                          // prologue
  for (int it = 0; it < NK; it += 2) {
    HALF(it, 0);
    HALF(it + 1, 1);
  }
#undef STAGE
#undef HALF

  // epilogue: C/D layout col=lane&15, row=(lane>>4)*4+reg (m89/m91-verified)
  const size_t rbase = (size_t)rbk * BM + wm + ((lane >> 4) * 4);
#pragma unroll
  for (int i = 0; i < 4; ++i)
#pragma unroll
    for (int j = 0; j < 2; ++j)
#pragma unroll
      for (int r = 0; r < 4; ++r) {
        size_t row = rbase + i * 16 + r;
        if (SILU) {
          float g = acc[0][i][j][r], u = acc[1][i][j][r];
          int col = by * 128 + wn + j * 16 + (lane & 15);
          Out[row * N_DIM + col] = f2bf(g * u / (1.f + __expf(-g)));
        } else {
#pragma unroll
          for (int nb = 0; nb < 2; ++nb) {
            int col = by * 256 + nb * 128 + wn + j * 16 + (lane & 15);
            Out[row * K_DIM + col] = f2bf(acc[nb][i][j][r]);
          }
        }
      }
}

// ---------------- gather: out[m] = w0*y[pos0] + w1*y[pos1] --------------------
__global__ __launch_bounds__(256) void gather_kernel(
    const u16* __restrict__ y, const float* __restrict__ tw,
    const int* __restrict__ pos_of, float* __restrict__ out) {
  int m = blockIdx.x;
  int k = threadIdx.x * 4;
  int p0 = pos_of[m * 2 + 0], p1 = pos_of[m * 2 + 1];
  float w0 = tw[m * 2 + 0], w1 = tw[m * 2 + 1];
  ushort4 y0 = *(const ushort4*)&y[(size_t)p0 * 1024 + k];
  ushort4 y1 = *(const ushort4*)&y[(size_t)p1 * 1024 + k];
  float4 o;
  o.x = w0 * bf2f(y0.x) + w1 * bf2f(y1.x);
  o.y = w0 * bf2f(y0.y) + w1 * bf2f(y1.y);
  o.z = w0 * bf2f(y0.z) + w1 * bf2f(y1.z);
  o.w = w0 * bf2f(y0.w) + w1 * bf2f(y1.w);
  *(float4*)&out[(size_t)m * 1024 + k] = o;
}

extern "C" void kernel_launch(void* const* d_in, const int* in_sizes, int n_in,
                              void* d_out, int out_size, void* d_ws, size_t ws_size,
                              hipStream_t stream) {
  const float* hs = (const float*)d_in[0];
  const float* w1 = (const float*)d_in[1];
  const float* w2 = (const float*)d_in[2];
  const float* tw = (const float*)d_in[3];
  const int* tids = (const int*)d_in[4];
  float* out = (float*)d_out;

  char* ws = (char*)d_ws;
  u16* hsb = (u16*)(ws);                                 //  8 MB  (M,K) bf16
  u16* w1t = (u16*)(ws + (size_t)(8u << 20));            // 32 MB  (E,2N,K) bf16
  u16* w2t = (u16*)(ws + (size_t)(40u << 20));           // 16 MB  (E,K,N)  bf16
  u16* h   = (u16*)(ws + (size_t)(56u << 20));           // 18 MB  (ROWS_CAP,N)
  u16* y   = (u16*)(ws + (size_t)(76u << 20));           // 18 MB  (ROWS_CAP,K)
  int* pair_token   = (int*)(ws + (size_t)(96u << 20));
  int* pos_of       = (int*)(ws + (size_t)(96u << 20) + 64 * 1024);
  int* block_expert = (int*)(ws + (size_t)(96u << 20) + 128 * 1024);
  int* blockhist    = (int*)(ws + (size_t)(96u << 20) + 192 * 1024);
  int* baseoff      = (int*)(ws + (size_t)(96u << 20) + 256 * 1024);

  prep_kernel<<<10240 + HBLK, 256, 0, stream>>>(hs, w1, w2, tids, hsb, w1t, w2t, blockhist);
  scan_kernel<<<1, 256, 0, stream>>>(blockhist, baseoff, pair_token, block_expert);
  assign_kernel<<<HBLK, 256, 0, stream>>>(tids, baseoff, pair_token, pos_of);
  gemm_big<true, true, 8><<<NROWBLK * 8, 512, 0, stream>>>(hsb, w1t, h, pair_token, block_expert);
  gemm_big<false, false, 4><<<NROWBLK * 4, 512, 0, stream>>>(h, w2t, y, pair_token, block_expert);
  gather_kernel<<<4096, 256, 0, stream>>>(y, tw, pos_of, out);
}